// Round 1
// baseline (245.563 us; speedup 1.0000x reference)
//
#include <hip/hip_runtime.h>
#include <math.h>

#define Bb 8
#define Nn 4096
#define Dd 768
#define PADDED 1024
#define D4 192      // Dd/4
#define NCHUNK 64   // n-chunks for the mean reduction
#define ROWS (Nn / NCHUNK)  // 64 rows per chunk

// ---------------- kernel 1a: partial column sums (no atomics) ----------------
// grid: Bb*NCHUNK blocks, 192 threads. partial[k][b][d] in ws.
__global__ void k_colsum_part(const float4* __restrict__ x4, float* __restrict__ partial) {
    int bid = blockIdx.x;
    int b = bid >> 6;            // /NCHUNK
    int k = bid & (NCHUNK - 1);
    int t = threadIdx.x;         // 0..191
    const float4* p = x4 + ((size_t)(b * Nn + k * ROWS) * D4) + t;
    float4 acc = {0.f, 0.f, 0.f, 0.f};
#pragma unroll 8
    for (int r = 0; r < ROWS; ++r) {
        float4 v = p[(size_t)r * D4];
        acc.x += v.x; acc.y += v.y; acc.z += v.z; acc.w += v.w;
    }
    float4* dst = (float4*)(partial + ((size_t)k * Bb + b) * Dd) + t;
    *dst = acc;
}

// ---------------- kernel 1b: atomic fallback (tiny ws) ----------------
__global__ void k_colsum_atomic(const float4* __restrict__ x4, float* __restrict__ c_sum) {
    int bid = blockIdx.x;
    int b = bid >> 6;
    int k = bid & (NCHUNK - 1);
    int t = threadIdx.x;
    const float4* p = x4 + ((size_t)(b * Nn + k * ROWS) * D4) + t;
    float4 acc = {0.f, 0.f, 0.f, 0.f};
#pragma unroll 8
    for (int r = 0; r < ROWS; ++r) {
        float4 v = p[(size_t)r * D4];
        acc.x += v.x; acc.y += v.y; acc.z += v.z; acc.w += v.w;
    }
    float* cs = c_sum + b * Dd + t * 4;
    atomicAdd(cs + 0, acc.x);
    atomicAdd(cs + 1, acc.y);
    atomicAdd(cs + 2, acc.z);
    atomicAdd(cs + 3, acc.w);
}

// ---------------- kernel 2: reduce chunks + WHT + weight ----------------
// grid: Bb blocks, PADDED(=1024) threads.
// src layout: [nchunks][Bb][Dd]; nchunks==1 for the atomic path.
__global__ void k_wht(const float* __restrict__ src, int nchunks,
                      const float* __restrict__ wht_weight,
                      float* __restrict__ cw) {
    __shared__ float s[PADDED];
    int b = blockIdx.x;
    int t = threadIdx.x;
    float v = 0.f;
    if (t < Dd) {
        float acc = 0.f;
        for (int k = 0; k < nchunks; ++k)
            acc += src[((size_t)k * Bb + b) * Dd + t];
        v = acc * (1.0f / (float)Nn);   // mean
    }
    s[t] = v;                            // zero-pad 768..1023
    __syncthreads();
    // 10-stage butterfly; matches reference ordering:
    //   bit clear: self + partner(at t+st);  bit set: partner(at t-st) - self
    for (int st = 1; st < PADDED; st <<= 1) {
        float a = s[t];
        float p = s[t ^ st];
        __syncthreads();
        s[t] = (t & st) ? (p - a) : (a + p);
        __syncthreads();
    }
    cw[b * PADDED + t] = s[t] * (1.0f / (float)PADDED) * wht_weight[t];
}

// ---------------- kernel 3: gate = sigmoid(cw @ gate_w.T + gate_b) ----------------
// grid: (3, Bb) blocks, 256 threads.
__global__ void k_gate(const float* __restrict__ cw, const float4* __restrict__ gw4,
                       const float* __restrict__ gate_b, float* __restrict__ gate) {
    __shared__ float s[PADDED];
    int b = blockIdx.y;
    int dchunk = blockIdx.x;
    int t = threadIdx.x;
    for (int i = t; i < PADDED; i += 256) s[i] = cw[b * PADDED + i];
    __syncthreads();
    int d = dchunk * 256 + t;
    const float4* w = gw4 + (size_t)d * (PADDED / 4);
    float acc = 0.f;
#pragma unroll 8
    for (int p = 0; p < PADDED / 4; ++p) {
        float4 wv = w[p];
        acc += s[4 * p] * wv.x + s[4 * p + 1] * wv.y
             + s[4 * p + 2] * wv.z + s[4 * p + 3] * wv.w;
    }
    float tsum = acc + gate_b[d];
    gate[b * Dd + d] = 1.0f / (1.0f + expf(-tsum));
}

// ---------------- kernel 4: out = x * gate ----------------
// grid: Bb*256 blocks, 192 threads; 16 rows per block, gate reused in-register.
__global__ void k_scale(const float4* __restrict__ x4, const float4* __restrict__ gate4,
                        float4* __restrict__ out4) {
    int bid = blockIdx.x;
    int b = bid >> 8;              // /256
    int n0 = (bid & 255) * 16;
    int t = threadIdx.x;           // 0..191
    float4 g = gate4[b * D4 + t];
    size_t base = ((size_t)(b * Nn + n0) * D4) + t;
#pragma unroll
    for (int r = 0; r < 16; ++r) {
        float4 v = x4[base + (size_t)r * D4];
        float4 o;
        o.x = v.x * g.x; o.y = v.y * g.y; o.z = v.z * g.z; o.w = v.w * g.w;
        out4[base + (size_t)r * D4] = o;
    }
}

extern "C" void kernel_launch(void* const* d_in, const int* in_sizes, int n_in,
                              void* d_out, int out_size, void* d_ws, size_t ws_size,
                              hipStream_t stream) {
    const float* x          = (const float*)d_in[0];
    const float* wht_weight = (const float*)d_in[1];
    const float* gate_w     = (const float*)d_in[2];
    const float* gate_b     = (const float*)d_in[3];
    float* out = (float*)d_out;

    // ws layout (big path): partial [NCHUNK][Bb][Dd] | cw [Bb][PADDED] | gate [Bb][Dd]
    size_t need_big = ((size_t)NCHUNK * Bb * Dd + (size_t)Bb * PADDED + (size_t)Bb * Dd) * 4;
    float* wsf = (float*)d_ws;

    if (ws_size >= need_big) {
        float* partial = wsf;
        float* cw   = partial + (size_t)NCHUNK * Bb * Dd;
        float* gate = cw + (size_t)Bb * PADDED;
        k_colsum_part<<<Bb * NCHUNK, 192, 0, stream>>>((const float4*)x, partial);
        k_wht<<<Bb, PADDED, 0, stream>>>(partial, NCHUNK, wht_weight, cw);
        k_gate<<<dim3(3, Bb), 256, 0, stream>>>(cw, (const float4*)gate_w, gate_b, gate);
        k_scale<<<Bb * 256, 192, 0, stream>>>((const float4*)x, (const float4*)gate, (float4*)out);
    } else {
        // tiny-ws fallback: atomics into c_sum
        float* c_sum = wsf;                         // Bb*Dd
        float* cw    = c_sum + (size_t)Bb * Dd;     // Bb*PADDED
        float* gate  = cw + (size_t)Bb * PADDED;    // Bb*Dd
        hipMemsetAsync(c_sum, 0, (size_t)Bb * Dd * sizeof(float), stream);
        k_colsum_atomic<<<Bb * NCHUNK, 192, 0, stream>>>((const float4*)x, c_sum);
        k_wht<<<Bb, PADDED, 0, stream>>>(c_sum, 1, wht_weight, cw);
        k_gate<<<dim3(3, Bb), 256, 0, stream>>>(cw, (const float4*)gate_w, gate_b, gate);
        k_scale<<<Bb * 256, 192, 0, stream>>>((const float4*)x, (const float4*)gate, (float4*)out);
    }
}